// Round 5
// baseline (616.753 us; speedup 1.0000x reference)
//
#include <hip/hip_runtime.h>
#include <hip/hip_bf16.h>

// EdgewiseReduce: out[n, :] = sum_{e : dst[e]==n} edge_data[e, :] * 0.5
// E = 1.6M, D = 32, N = 100K.
//
// History:
//  R1: 51.2M f32 global atomics -> 819 MB of 16B txns, 647 us (atomic-bound).
//  R2: counting sort; random 4B scatter -> 106 MB line writebacks, 494 us.
//  R3: replicated scan -> 1.6 GB L3 traffic, latency-bound, 378 us.
//  R4: two-level bucket sort OK (gather WRITE=12.5MB exact) but gather was
//      latency-serialized: 2-deep chain, 352 GB/s, VALUBusy 1.1%, 340 us.
// R5: gather restructured for guaranteed MLP: ids staged through LDS,
//     8 independent float4 row loads held in registers before any use,
//     native ds_add_f32 accumulate (stride-33 banks). int4 dst reads in
//     hist/scatter.

#define D 32
#define FACTOR 0.5f
#define BSHIFT 7                 // 128 nodes per bucket
#define BNODES (1 << BSHIFT)

// ---------- K1: global bucket histogram (int4 loads) ----------
__global__ void hist_kernel(const int* __restrict__ dst, int* __restrict__ ghist,
                            int E, int N, int nb) {
  extern __shared__ int lhist[];
  for (int i = threadIdx.x; i < nb; i += blockDim.x) lhist[i] = 0;
  __syncthreads();
  const int4* dst4 = (const int4*)dst;
  int E4 = E >> 2;
  for (int i = blockIdx.x * blockDim.x + threadIdx.x; i < E4;
       i += gridDim.x * blockDim.x) {
    int4 v = dst4[i];
    if ((unsigned)v.x < (unsigned)N) atomicAdd(&lhist[v.x >> BSHIFT], 1);
    if ((unsigned)v.y < (unsigned)N) atomicAdd(&lhist[v.y >> BSHIFT], 1);
    if ((unsigned)v.z < (unsigned)N) atomicAdd(&lhist[v.z >> BSHIFT], 1);
    if ((unsigned)v.w < (unsigned)N) atomicAdd(&lhist[v.w >> BSHIFT], 1);
  }
  // tail
  int t = (E4 << 2) + blockIdx.x * blockDim.x + threadIdx.x;
  if (t < E) {
    int d = dst[t];
    if ((unsigned)d < (unsigned)N) atomicAdd(&lhist[d >> BSHIFT], 1);
  }
  __syncthreads();
  for (int i = threadIdx.x; i < nb; i += blockDim.x)
    if (lhist[i]) atomicAdd(&ghist[i], lhist[i]);
}

// ---------- K2: exclusive scan over nb (<=1024) buckets, one block ----------
__global__ void scan_kernel(const int* __restrict__ ghist, int* __restrict__ bases,
                            int* __restrict__ cursor, int nb) {
  __shared__ int buf[1024];
  int x = threadIdx.x;
  int v = (x < nb) ? ghist[x] : 0;
  buf[x] = v;
  __syncthreads();
  for (int off = 1; off < 1024; off <<= 1) {
    int t = (x >= off) ? buf[x - off] : 0;
    __syncthreads();
    buf[x] += t;
    __syncthreads();
  }
  if (x < nb) {
    int b = buf[x] - v;
    bases[x] = b;
    cursor[x] = b;
  }
}

// ---------- K3: per-block reserve + scatter packed ids (int4 loads) ----------
__global__ void scatter_kernel(const int* __restrict__ dst, int* __restrict__ gcursor,
                               int* __restrict__ order, int E, int N, int nb,
                               int chunk) {
  extern __shared__ int sm[];
  int* lhist = sm;            // [nb]
  int* lcur = sm + nb;        // [nb]
  int lo = blockIdx.x * chunk;          // chunk is 4-aligned
  int hiE = min(lo + chunk, E);
  const int4* dst4 = (const int4*)dst;

  for (int i = threadIdx.x; i < nb; i += blockDim.x) lhist[i] = 0;
  __syncthreads();

  int lo4 = lo >> 2;
  int full4 = (hiE - lo) >> 2;          // full int4s in [lo, hiE)
  for (int i = threadIdx.x; i < full4; i += blockDim.x) {
    int4 v = dst4[lo4 + i];
    if ((unsigned)v.x < (unsigned)N) atomicAdd(&lhist[v.x >> BSHIFT], 1);
    if ((unsigned)v.y < (unsigned)N) atomicAdd(&lhist[v.y >> BSHIFT], 1);
    if ((unsigned)v.z < (unsigned)N) atomicAdd(&lhist[v.z >> BSHIFT], 1);
    if ((unsigned)v.w < (unsigned)N) atomicAdd(&lhist[v.w >> BSHIFT], 1);
  }
  int tb = lo + (full4 << 2) + threadIdx.x;
  if (tb < hiE) {
    int d = dst[tb];
    if ((unsigned)d < (unsigned)N) atomicAdd(&lhist[d >> BSHIFT], 1);
  }
  __syncthreads();

  for (int i = threadIdx.x; i < nb; i += blockDim.x) {
    int c = lhist[i];
    lcur[i] = c ? atomicAdd(&gcursor[i], c) : 0;
  }
  __syncthreads();

  for (int i = threadIdx.x; i < full4; i += blockDim.x) {
    int e = lo + (i << 2);
    int4 v = dst4[lo4 + i];
    if ((unsigned)v.x < (unsigned)N)
      order[atomicAdd(&lcur[v.x >> BSHIFT], 1)] = ((e + 0) << BSHIFT) | (v.x & (BNODES - 1));
    if ((unsigned)v.y < (unsigned)N)
      order[atomicAdd(&lcur[v.y >> BSHIFT], 1)] = ((e + 1) << BSHIFT) | (v.y & (BNODES - 1));
    if ((unsigned)v.z < (unsigned)N)
      order[atomicAdd(&lcur[v.z >> BSHIFT], 1)] = ((e + 2) << BSHIFT) | (v.z & (BNODES - 1));
    if ((unsigned)v.w < (unsigned)N)
      order[atomicAdd(&lcur[v.w >> BSHIFT], 1)] = ((e + 3) << BSHIFT) | (v.w & (BNODES - 1));
  }
  if (tb < hiE) {
    int d = dst[tb];
    if ((unsigned)d < (unsigned)N)
      order[atomicAdd(&lcur[d >> BSHIFT], 1)] = (tb << BSHIFT) | (d & (BNODES - 1));
  }
}

// ---------- K4: gather-reduce per bucket, deep-MLP ----------
#define K4_THREADS 512
#define STAGE 1024
__global__ __launch_bounds__(K4_THREADS)
void gather_kernel(const float4* __restrict__ data, const int* __restrict__ order,
                   const int* __restrict__ bases, const int* __restrict__ ghist,
                   float4* __restrict__ out, int N) {
  __shared__ float acc[BNODES * 33];   // 16896 B, bank = (node + 4q + c) % 32
  __shared__ int stage[STAGE];         // 4096 B id staging
  int b = blockIdx.x;
  int base = bases[b];
  int count = ghist[b];
  int lo = b << BSHIFT;

  for (int i = threadIdx.x; i < BNODES * 33; i += K4_THREADS) acc[i] = 0.f;

  const int q = threadIdx.x & 7;       // float4 slot within row
  const int g = threadIdx.x >> 3;      // group 0..63

  for (int c0 = 0; c0 < count; c0 += STAGE) {
    int csz = min(STAGE, count - c0);
    __syncthreads();                    // acc/stage ready for reuse
    for (int i = threadIdx.x; i < csz; i += K4_THREADS)
      stage[i] = order[base + c0 + i];
    __syncthreads();

    // group g consumes stage[g + 64k]; batches of 8 ids held in registers
    for (int k0 = 0; k0 < STAGE / 64; k0 += 8) {
      int idx[8];
      float4 v[8];
      #pragma unroll
      for (int u = 0; u < 8; ++u) {
        int j = g + 64 * (k0 + u);
        idx[u] = (j < csz) ? stage[j] : -1;
      }
      #pragma unroll
      for (int u = 0; u < 8; ++u)
        if (idx[u] >= 0)
          v[u] = data[(size_t)(idx[u] >> BSHIFT) * 8 + q];   // 8 loads in flight
      #pragma unroll
      for (int u = 0; u < 8; ++u) {
        if (idx[u] >= 0) {
          float* a = &acc[(idx[u] & (BNODES - 1)) * 33 + q * 4];
          unsafeAtomicAdd(a + 0, v[u].x);
          unsafeAtomicAdd(a + 1, v[u].y);
          unsafeAtomicAdd(a + 2, v[u].z);
          unsafeAtomicAdd(a + 3, v[u].w);
        }
      }
    }
  }
  __syncthreads();

  int nlocal = min(BNODES, N - lo);
  for (int t = threadIdx.x; t < nlocal * 8; t += K4_THREADS) {
    int r = t >> 3, jq = t & 7;
    const float* a = &acc[r * 33 + jq * 4];
    float4 v;
    v.x = a[0] * FACTOR; v.y = a[1] * FACTOR;
    v.z = a[2] * FACTOR; v.w = a[3] * FACTOR;
    out[(size_t)(lo + r) * 8 + jq] = v;
  }
}

// ---------- Fallback: round-1 atomic scatter ----------
__global__ void atomic_kernel(const float4* __restrict__ edge_data,
                              const int* __restrict__ edge_dst,
                              float* __restrict__ out, int E, int N) {
  int tid = blockIdx.x * blockDim.x + threadIdx.x;
  int e = tid >> 3;
  int q = tid & 7;
  if (e >= E) return;
  int dst = edge_dst[e];
  if (dst < 0 || dst >= N) return;
  float4 v = edge_data[(size_t)e * 8 + q];
  float* p = out + (size_t)dst * D + q * 4;
  unsafeAtomicAdd(p + 0, v.x * FACTOR);
  unsafeAtomicAdd(p + 1, v.y * FACTOR);
  unsafeAtomicAdd(p + 2, v.z * FACTOR);
  unsafeAtomicAdd(p + 3, v.w * FACTOR);
}

extern "C" void kernel_launch(void* const* d_in, const int* in_sizes, int n_in,
                              void* d_out, int out_size, void* d_ws, size_t ws_size,
                              hipStream_t stream) {
  const float4* edge_data = (const float4*)d_in[0];
  const int* edge_dst = (const int*)d_in[1];

  int E = in_sizes[1];
  int N = out_size / D;

  int nb = (N + BNODES - 1) >> BSHIFT;            // 782 for N=100K
  size_t need = ((size_t)3 * nb + (size_t)E) * sizeof(int);
  bool pack_ok = ((long long)E << BSHIFT) < (1ll << 31);

  if (nb > 1024 || ws_size < need || !pack_ok) {
    float* out = (float*)d_out;
    hipMemsetAsync(d_out, 0, (size_t)out_size * sizeof(float), stream);
    int total = E * 8;
    atomic_kernel<<<(total + 255) / 256, 256, 0, stream>>>(edge_data, edge_dst, out, E, N);
    return;
  }

  int* ws = (int*)d_ws;
  int* ghist  = ws;                // [nb]
  int* bases  = ws + nb;           // [nb]
  int* cursor = ws + 2 * nb;       // [nb]
  int* order  = ws + 3 * nb;       // [E]

  hipMemsetAsync(ghist, 0, (size_t)nb * sizeof(int), stream);

  size_t lds1 = (size_t)nb * sizeof(int);
  hist_kernel<<<512, 256, lds1, stream>>>(edge_dst, ghist, E, N, nb);

  scan_kernel<<<1, 1024, 0, stream>>>(ghist, bases, cursor, nb);

  int chunk = ((E + 255) / 256 + 3) & ~3;         // 4-aligned per-block chunk
  size_t lds3 = (size_t)2 * nb * sizeof(int);
  scatter_kernel<<<256, 256, lds3, stream>>>(edge_dst, cursor, order, E, N, nb, chunk);

  gather_kernel<<<nb, K4_THREADS, 0, stream>>>(
      edge_data, order, bases, ghist, (float4*)d_out, N);
}